// Round 15
// baseline (805.196 us; speedup 1.0000x reference)
//
#include <hip/hip_runtime.h>
#include <math.h>

namespace {

constexpr int BTOT = 131072;
constexpr int HN = 24;
constexpr int NO = 24;
constexpr int NSTEPS = 23;
constexpr int WIH_STRIDE = 100;

// XLA:GPU(ROCm): logistic = 1/(1+exp(-x)) with native ocml expf.
__device__ __forceinline__ float xsig(float x) {
#pragma clang fp contract(off)
  return 1.0f / (1.0f + expf(-x));
}

// XLA:GPU row-reduce, extent 24 (pow2-padded to 32 lanes, init 0):
// shuffle-down tree offsets 16,8,4,2,1.
__device__ __forceinline__ float vsum24(const float* x) {
#pragma clang fp contract(off)
  float L[8];
#pragma unroll
  for (int j = 0; j < 8; ++j) L[j] = (x[j] + x[j + 16]) + x[j + 8];
  float b0 = L[0] + L[4];
  float b1 = L[1] + L[5];
  float b2 = L[2] + L[6];
  float b3 = L[3] + L[7];
  return (b0 + b2) + (b1 + b3);
}

// jax.lax.associative_scan(add), compile-time N in [2,11]. Same recursion
// as the verified runtime ascan11 (r2 zero-init preserved).
template <int N>
__device__ __forceinline__ void ascanT(float* x) {
#pragma clang fp contract(off)
  constexpr int m1 = N >> 1;
  float r1[5];
#pragma unroll
  for (int i = 0; i < 5; ++i)
    if (2 * i + 1 < N) r1[i] = x[2 * i] + x[2 * i + 1];
  float r2[2] = {0.f, 0.f};
#pragma unroll
  for (int i = 0; i < 2; ++i)
    if (2 * i + 1 < m1) r2[i] = r1[2 * i] + r1[2 * i + 1];
  constexpr int m2 = m1 >> 1;
  float s2[2];
  s2[0] = r2[0];
  s2[1] = (m2 == 2) ? (r2[0] + r2[1]) : r2[1];
  float s1[5];
  s1[0] = r1[0];
  if (1 < m1) s1[1] = s2[0];
  if (2 < m1) s1[2] = s2[0] + r1[2];
  if (3 < m1) s1[3] = s2[1];
  if (4 < m1) s1[4] = s2[1] + r1[4];
  float o[11];
  o[0] = x[0];
#pragma unroll
  for (int i = 0; i < 5; ++i) {
    if (2 * i + 1 < N) o[2 * i + 1] = s1[i];
    if (2 * i + 2 < N) o[2 * i + 2] = s1[i] + x[2 * i + 2];
  }
#pragma unroll
  for (int i = 0; i < 11; ++i)
    if (i < N) x[i] = o[i];
}

// Slice softmax + inverse-CDF sample, COUNT compile-time.
// Bitwise-identical to the verified runtime path for n=COUNT.
template <int COUNT, int ADD>
__device__ __forceinline__ void sample_slice(const float* pslice, float ssum,
                                             float u, int* sel_out,
                                             float* pr_out) {
#pragma clang fp contract(off)
  float q[COUNT];
#pragma unroll
  for (int j = 0; j < COUNT; ++j) q[j] = pslice[j] / ssum;
  float m2 = q[0];
#pragma unroll
  for (int j = 1; j < COUNT; ++j) m2 = fmaxf(m2, q[j]);
#pragma unroll
  for (int j = 0; j < COUNT; ++j) q[j] = expf(q[j] - m2);
  float qsum;
  if constexpr (COUNT < 8) {
    // vector loop 0 iterations -> sequential scalar, init 0
    float s = 0.f;
#pragma unroll
    for (int j = 0; j < COUNT; ++j) s = s + q[j];
    qsum = s;
  } else {
    // pow2-pad to 16 (pads exact +0), shuffle tree 8,4,2,1
    float t[16];
#pragma unroll
    for (int l = 0; l < 16; ++l) t[l] = (l < COUNT) ? q[l] : 0.f;
    float a[8], b[4], c2[2];
#pragma unroll
    for (int l = 0; l < 8; ++l) a[l] = t[l] + t[l + 8];
#pragma unroll
    for (int l = 0; l < 4; ++l) b[l] = a[l] + a[l + 4];
#pragma unroll
    for (int l = 0; l < 2; ++l) c2[l] = b[l] + b[l + 2];
    qsum = c2[0] + c2[1];
  }
  float dag[COUNT];
#pragma unroll
  for (int j = 0; j < COUNT; ++j) dag[j] = q[j] / qsum;
  float cs[COUNT];
#pragma unroll
  for (int j = 0; j < COUNT; ++j) cs[j] = dag[j];
  ascanT<COUNT>(cs);
  int idx = -1;
  float pr = 0.f;
#pragma unroll
  for (int j = 0; j < COUNT; ++j) {
    const bool take = (idx < 0) && (cs[j] > u);
    idx = take ? j : idx;
    pr = take ? dag[j] : pr;
  }
  if (idx < 0) { idx = 0; pr = dag[0]; }  // argmax(all False) = 0
  *sel_out = idx + ADD;
  *pr_out = pr;
}

// LSTM cell (x = one-hot column xcol of W_ih, or zeros when xcol<0).
__device__ __forceinline__ void lstm_cell(float* h, float* c, int xcol,
                                          const float* s_wih,
                                          const float* __restrict__ W_hh,
                                          const float* __restrict__ b_ih,
                                          const float* __restrict__ b_hh) {
#pragma clang fp contract(off)
  const bool hasx = (xcol >= 0);
  const int xc = hasx ? xcol : 0;
  float hn[HN];
#pragma unroll
  for (int j = 0; j < HN; ++j) {
    const float4 wv =
        *reinterpret_cast<const float4*>(&s_wih[xc * WIH_STRIDE + j * 4]);
    float ai = 0.f, af = 0.f, ag = 0.f, ao = 0.f;
#pragma unroll
    for (int k = 0; k < HN; ++k) {
      const float hk = h[k];
      ai = fmaf(W_hh[(j)*HN + k], hk, ai);
      af = fmaf(W_hh[(j + 24) * HN + k], hk, af);
      ag = fmaf(W_hh[(j + 48) * HN + k], hk, ag);
      ao = fmaf(W_hh[(j + 72) * HN + k], hk, ao);
    }
    const float gi = (((hasx ? wv.x : 0.f) + ai) + b_ih[j]) + b_hh[j];
    const float gf = (((hasx ? wv.y : 0.f) + af) + b_ih[j + 24]) + b_hh[j + 24];
    const float gg = (((hasx ? wv.z : 0.f) + ag) + b_ih[j + 48]) + b_hh[j + 48];
    const float go = (((hasx ? wv.w : 0.f) + ao) + b_ih[j + 72]) + b_hh[j + 72];
    const float t1 = xsig(gf) * c[j];
    const float t2 = xsig(gi) * tanhf(gg);
    const float c2 = t1 + t2;
    c[j] = c2;
    hn[j] = xsig(go) * tanhf(c2);
  }
#pragma unroll
  for (int j = 0; j < HN; ++j) h[j] = hn[j];
}

// p = exp(logits - max) over 24; returns XLA shuffle-tree ssum.
__device__ __forceinline__ float logits_exp(const float* h, float* p,
                                            const float* __restrict__ W_lin,
                                            const float* __restrict__ b_lin) {
#pragma clang fp contract(off)
#pragma unroll
  for (int o = 0; o < NO; ++o) {
    float a = 0.f;
#pragma unroll
    for (int k = 0; k < HN; ++k) a = fmaf(W_lin[o * HN + k], h[k], a);
    p[o] = a + b_lin[o];
  }
  float m = p[0];
#pragma unroll
  for (int o = 1; o < NO; ++o) m = fmaxf(m, p[o]);
#pragma unroll
  for (int o = 0; o < NO; ++o) p[o] = expf(p[o] - m);
  return vsum24(p);
}

__global__ __launch_bounds__(256, 1) void policy_kernel(
    const float* __restrict__ W_ih, const float* __restrict__ W_hh,
    const float* __restrict__ b_ih, const float* __restrict__ b_hh,
    const float* __restrict__ W_lin, const float* __restrict__ b_lin,
    const float* __restrict__ rand_u, float* __restrict__ out) {
#pragma clang fp contract(off)
  __shared__ __align__(16) float s_wih[23 * WIH_STRIDE];
  for (int t = threadIdx.x; t < 23 * 96; t += 256) {
    const int col = t / 96;
    const int r = t - col * 96;
    s_wih[col * WIH_STRIDE + r] = W_ih[((r & 3) * 24 + (r >> 2)) * NO + col];
  }
  __syncthreads();

  const int e = blockIdx.x * 256 + threadIdx.x;
  float* actions = out;                    // [B][24]
  float* probs = out + (size_t)BTOT * NO;  // [B][23]

  float h[HN], c[HN];
#pragma unroll
  for (int k = 0; k < HN; ++k) { h[k] = 0.f; c[k] = 0.f; }

  int x_idx = -1;
  int step = 0;
  actions[(size_t)e * NO + 23] = 0.0f;

#pragma unroll 1
  for (int counter = 0; counter < 12; ++counter) {
    // ---------- DAG/father step (counter > 0) ----------
    if (counter > 0) {
      lstm_cell(h, c, x_idx, s_wih, W_hh, b_ih, b_hh);
      if (counter == 1) {
        // softmax(p[12:13]) = [1.0] exactly; cs[0]=1.0>u always -> idx 0.
        actions[(size_t)e * NO + step] = 12.0f;
        probs[(size_t)e * NSTEPS + step] = 1.0f;
        x_idx = 12;
      } else {
        float p[NO];
        const float ssum = logits_exp(h, p, W_lin, b_lin);
        const float u = rand_u[(size_t)step * BTOT + e];
        int sel;
        float pr;
        switch (counter) {
          case 2: sample_slice<2, 12>(p + 12, ssum, u, &sel, &pr); break;
          case 3: sample_slice<3, 12>(p + 12, ssum, u, &sel, &pr); break;
          case 4: sample_slice<4, 12>(p + 12, ssum, u, &sel, &pr); break;
          case 5: sample_slice<5, 12>(p + 12, ssum, u, &sel, &pr); break;
          case 6: sample_slice<6, 12>(p + 12, ssum, u, &sel, &pr); break;
          case 7: sample_slice<7, 12>(p + 12, ssum, u, &sel, &pr); break;
          case 8: sample_slice<8, 12>(p + 12, ssum, u, &sel, &pr); break;
          case 9: sample_slice<9, 12>(p + 12, ssum, u, &sel, &pr); break;
          case 10: sample_slice<10, 12>(p + 12, ssum, u, &sel, &pr); break;
          default: sample_slice<11, 12>(p + 12, ssum, u, &sel, &pr); break;
        }
        actions[(size_t)e * NO + step] = (float)sel;
        probs[(size_t)e * NSTEPS + step] = (float)pr;
        x_idx = sel;
      }
      ++step;
    }

    // ---------- action step ----------
    if (counter == 0) {
      // h==c==x==0: gates reduce bitwise to ((0+0)+b_ih)+b_hh.
#pragma unroll
      for (int j = 0; j < HN; ++j) {
        const float gi = ((0.0f + 0.0f) + b_ih[j]) + b_hh[j];
        const float gf = ((0.0f + 0.0f) + b_ih[j + 24]) + b_hh[j + 24];
        const float gg = ((0.0f + 0.0f) + b_ih[j + 48]) + b_hh[j + 48];
        const float go = ((0.0f + 0.0f) + b_ih[j + 72]) + b_hh[j + 72];
        const float t1 = xsig(gf) * c[j];
        const float t2 = xsig(gi) * tanhf(gg);
        const float c2 = t1 + t2;
        c[j] = c2;
        h[j] = xsig(go) * tanhf(c2);
      }
    } else {
      lstm_cell(h, c, x_idx, s_wih, W_hh, b_ih, b_hh);
    }
    {
      float p[NO];
      const float ssum = logits_exp(h, p, W_lin, b_lin);
      const float u = rand_u[(size_t)step * BTOT + e];
      int sel;
      float pr;
      sample_slice<11, 1>(p, ssum, u, &sel, &pr);
      actions[(size_t)e * NO + step] = (float)sel;
      probs[(size_t)e * NSTEPS + step] = (float)pr;
      x_idx = sel;
      ++step;
    }
  }
}

}  // namespace

extern "C" void kernel_launch(void* const* d_in, const int* in_sizes, int n_in,
                              void* d_out, int out_size, void* d_ws, size_t ws_size,
                              hipStream_t stream) {
  const float* W_ih = (const float*)d_in[0];
  const float* W_hh = (const float*)d_in[1];
  const float* b_ih = (const float*)d_in[2];
  const float* b_hh = (const float*)d_in[3];
  const float* W_lin = (const float*)d_in[4];
  const float* b_lin = (const float*)d_in[5];
  const float* rand_u = (const float*)d_in[6];
  float* out = (float*)d_out;
  policy_kernel<<<dim3(BTOT / 256), dim3(256), 0, stream>>>(
      W_ih, W_hh, b_ih, b_hh, W_lin, b_lin, rand_u, out);
}

// Round 16
// 756.057 us; speedup vs baseline: 1.0650x; 1.0650x over previous
//
#include <hip/hip_runtime.h>
#include <math.h>

namespace {

constexpr int BTOT = 131072;
constexpr int HN = 24;
constexpr int NO = 24;
constexpr int NSTEPS = 23;
constexpr int WIH_STRIDE = 100;

// XLA:GPU(ROCm): logistic = 1/(1+exp(-x)) with native ocml expf.
__device__ __forceinline__ float xsig(float x) {
#pragma clang fp contract(off)
  return 1.0f / (1.0f + expf(-x));
}

// XLA:GPU row-reduce, extent 24 (pow2-padded to 32 lanes, init 0):
// shuffle-down tree offsets 16,8,4,2,1.
__device__ __forceinline__ float vsum24(const float* x) {
#pragma clang fp contract(off)
  float L[8];
#pragma unroll
  for (int j = 0; j < 8; ++j) L[j] = (x[j] + x[j + 16]) + x[j + 8];
  float b0 = L[0] + L[4];
  float b1 = L[1] + L[5];
  float b2 = L[2] + L[6];
  float b3 = L[3] + L[7];
  return (b0 + b2) + (b1 + b3);
}

// XLA:GPU row-reduce, extent n<=11 (pow2-padded to 16, init 0) — tree for
// ALL n (verified: R11-R14 pass with this; R15's n<8-sequential deviation
// doubled absmax).
__device__ __forceinline__ float vsumN(const float* x, int n) {
#pragma clang fp contract(off)
  float t[16];
#pragma unroll
  for (int l = 0; l < 16; ++l) t[l] = (l < n) ? x[l] : 0.f;
  float a[8], b[4], c[2];
#pragma unroll
  for (int l = 0; l < 8; ++l) a[l] = t[l] + t[l + 8];
#pragma unroll
  for (int l = 0; l < 4; ++l) b[l] = a[l] + a[l + 4];
#pragma unroll
  for (int l = 0; l < 2; ++l) c[l] = b[l] + b[l + 2];
  return c[0] + c[1];
}

// jax.lax.associative_scan(add) exact clone for n in [1,11].
__device__ __forceinline__ void ascan11(float* x, int n) {
#pragma clang fp contract(off)
  if (n < 2) return;
  const int m1 = n >> 1;
  float r1[5];
#pragma unroll
  for (int i = 0; i < 5; ++i)
    if (2 * i + 1 < n) r1[i] = x[2 * i] + x[2 * i + 1];
  float r2[2] = {0.f, 0.f};
#pragma unroll
  for (int i = 0; i < 2; ++i)
    if (2 * i + 1 < m1) r2[i] = r1[2 * i] + r1[2 * i + 1];
  const int m2 = m1 >> 1;
  float s2[2];
  s2[0] = r2[0];
  s2[1] = (m2 == 2) ? (r2[0] + r2[1]) : r2[1];
  float s1[5];
  s1[0] = r1[0];
  if (1 < m1) s1[1] = s2[0];
  if (2 < m1) s1[2] = s2[0] + r1[2];
  if (3 < m1) s1[3] = s2[1];
  if (4 < m1) s1[4] = s2[1] + r1[4];
  float o[11];
  o[0] = x[0];
#pragma unroll
  for (int i = 0; i < 5; ++i) {
    if (2 * i + 1 < n) o[2 * i + 1] = s1[i];
    if (2 * i + 2 < n) o[2 * i + 2] = s1[i] + x[2 * i + 2];
  }
#pragma unroll
  for (int i = 0; i < 11; ++i)
    if (i < n) x[i] = o[i];
}

__global__ __launch_bounds__(256, 1) void policy_kernel(
    const float* __restrict__ W_ih, const float* __restrict__ W_hh,
    const float* __restrict__ b_ih, const float* __restrict__ b_hh,
    const float* __restrict__ W_lin, const float* __restrict__ b_lin,
    const float* __restrict__ rand_u, float* __restrict__ out) {
#pragma clang fp contract(off)
  __shared__ __align__(16) float s_wih[23 * WIH_STRIDE];
  for (int t = threadIdx.x; t < 23 * 96; t += 256) {
    const int col = t / 96;
    const int r = t - col * 96;
    s_wih[col * WIH_STRIDE + r] = W_ih[((r & 3) * 24 + (r >> 2)) * NO + col];
  }
  __syncthreads();

  const int e = blockIdx.x * 256 + threadIdx.x;
  float* actions = out;                    // [B][24]
  float* probs = out + (size_t)BTOT * NO;  // [B][23]

  float h[HN], c[HN];
#pragma unroll
  for (int k = 0; k < HN; ++k) { h[k] = 0.f; c[k] = 0.f; }

  int x_idx = -1;  // -1 => x all zeros (first step)
  int step = 0;
  actions[(size_t)e * NO + 23] = 0.0f;

#pragma unroll 1
  for (int counter = 0; counter < 12; ++counter) {
#pragma unroll 1
    for (int sub = (counter == 0) ? 1 : 0; sub < 2; ++sub) {
      const bool first_step = (counter == 0 && sub == 1);

      // ===== LSTM cell =====
      if (first_step) {
        // h==0, c==0, x==0 exactly: gates reduce bitwise to ((0+0)+b_ih)+b_hh
#pragma unroll
        for (int j = 0; j < HN; ++j) {
          const float gi = ((0.0f + 0.0f) + b_ih[j]) + b_hh[j];
          const float gf = ((0.0f + 0.0f) + b_ih[j + 24]) + b_hh[j + 24];
          const float gg = ((0.0f + 0.0f) + b_ih[j + 48]) + b_hh[j + 48];
          const float go = ((0.0f + 0.0f) + b_ih[j + 72]) + b_hh[j + 72];
          const float t1 = xsig(gf) * c[j];
          const float t2 = xsig(gi) * tanhf(gg);
          const float c2 = t1 + t2;
          c[j] = c2;
          h[j] = xsig(go) * tanhf(c2);
        }
      } else {
        // counter==1 action step always has x_idx==12 (proven deterministic)
        const int xcol = (counter == 1 && sub == 1) ? 12 : x_idx;
        float hn[HN];
#pragma unroll
        for (int j = 0; j < HN; ++j) {
          const float4 wv =
              *reinterpret_cast<const float4*>(&s_wih[xcol * WIH_STRIDE + j * 4]);
          float ai = 0.f, af = 0.f, ag = 0.f, ao = 0.f;
#pragma unroll
          for (int k = 0; k < HN; ++k) {
            const float hk = h[k];
            ai = fmaf(W_hh[(j)*HN + k], hk, ai);
            af = fmaf(W_hh[(j + 24) * HN + k], hk, af);
            ag = fmaf(W_hh[(j + 48) * HN + k], hk, ag);
            ao = fmaf(W_hh[(j + 72) * HN + k], hk, ao);
          }
          const float gi = ((wv.x + ai) + b_ih[j]) + b_hh[j];
          const float gf = ((wv.y + af) + b_ih[j + 24]) + b_hh[j + 24];
          const float gg = ((wv.z + ag) + b_ih[j + 48]) + b_hh[j + 48];
          const float go = ((wv.w + ao) + b_ih[j + 72]) + b_hh[j + 72];
          const float t1 = xsig(gf) * c[j];
          const float t2 = xsig(gi) * tanhf(gg);
          const float c2 = t1 + t2;
          c[j] = c2;
          hn[j] = xsig(go) * tanhf(c2);
        }
#pragma unroll
        for (int j = 0; j < HN; ++j) h[j] = hn[j];
      }

      // ===== counter==1 DAG step: deterministic sample =====
      if (sub == 0 && counter == 1) {
        actions[(size_t)e * NO + step] = 12.0f;
        probs[(size_t)e * NSTEPS + step] = 1.0f;
        x_idx = 12;
        ++step;
        continue;
      }

      // ===== p-logits + exp (GPU shuffle-tree sum over 24) =====
      float p[NO];
#pragma unroll
      for (int o = 0; o < NO; ++o) {
        float a = 0.f;
#pragma unroll
        for (int k = 0; k < HN; ++k) a = fmaf(W_lin[o * HN + k], h[k], a);
        p[o] = a + b_lin[o];
      }
      float m = p[0];
#pragma unroll
      for (int o = 1; o < NO; ++o) m = fmaxf(m, p[o]);
#pragma unroll
      for (int o = 0; o < NO; ++o) p[o] = expf(p[o] - m);
      const float ssum = vsum24(p);

      // ===== slice softmax + tree cumsum sample =====
      const int count = (sub == 0) ? counter : 11;
      const int add = (sub == 0) ? 12 : 1;
      float q[11];
#pragma unroll
      for (int jj = 0; jj < 11; ++jj)
        q[jj] = ((sub == 0) ? p[12 + jj] : p[jj]) / ssum;

      const float u = rand_u[(size_t)step * BTOT + e];
      float m2 = q[0];
#pragma unroll
      for (int jj = 1; jj < 11; ++jj)
        if (jj < count) m2 = fmaxf(m2, q[jj]);
#pragma unroll
      for (int jj = 0; jj < 11; ++jj)
        if (jj < count) q[jj] = expf(q[jj] - m2);
      const float qsum = vsumN(q, count);
      float dag[11];
#pragma unroll
      for (int jj = 0; jj < 11; ++jj)
        dag[jj] = (jj < count) ? (q[jj] / qsum) : 0.f;

      float cs[11];
#pragma unroll
      for (int jj = 0; jj < 11; ++jj) cs[jj] = dag[jj];
      ascan11(cs, count);  // jax associative_scan tree

      int idx = -1;
      float pr = 0.f;
#pragma unroll
      for (int jj = 0; jj < 11; ++jj)
        if (jj < count) {
          const bool take = (idx < 0) && (cs[jj] > u);
          idx = take ? jj : idx;
          pr = take ? dag[jj] : pr;
        }
      if (idx < 0) { idx = 0; pr = dag[0]; }  // argmax(all False) = 0

      const int sel = idx + add;
      actions[(size_t)e * NO + step] = (float)sel;
      probs[(size_t)e * NSTEPS + step] = (float)pr;
      x_idx = sel;
      ++step;
    }
  }
}

}  // namespace

extern "C" void kernel_launch(void* const* d_in, const int* in_sizes, int n_in,
                              void* d_out, int out_size, void* d_ws, size_t ws_size,
                              hipStream_t stream) {
  const float* W_ih = (const float*)d_in[0];
  const float* W_hh = (const float*)d_in[1];
  const float* b_ih = (const float*)d_in[2];
  const float* b_hh = (const float*)d_in[3];
  const float* W_lin = (const float*)d_in[4];
  const float* b_lin = (const float*)d_in[5];
  const float* rand_u = (const float*)d_in[6];
  float* out = (float*)d_out;
  policy_kernel<<<dim3(BTOT / 256), dim3(256), 0, stream>>>(
      W_ih, W_hh, b_ih, b_hh, W_lin, b_lin, rand_u, out);
}